// Round 1
// 1444.472 us; speedup vs baseline: 1.0442x; 1.0442x over previous
//
#include <hip/hip_runtime.h>
#include <stdint.h>

#define BSZ   128
#define PDIM  196
#define EDIM  512
#define HDIM  512
#define ADIM  256
#define VDIM  30000
#define VPAD  30080
#define NSTEP 20
#define KCAT  1536
#define KSTEP 1024
#define NGATE 2048
#define KSPLIT 8

typedef __attribute__((ext_vector_type(8))) short short8;
typedef __attribute__((ext_vector_type(4))) float f32x4;

__device__ __forceinline__ unsigned short f2b(float f) {
  union { float f; uint32_t u; } v; v.f = f;
  uint32_t r = v.u + 0x7fffu + ((v.u >> 16) & 1u);
  return (unsigned short)(r >> 16);
}
__device__ __forceinline__ float b2f(unsigned short u) {
  union { uint32_t u; float f; } v; v.u = ((uint32_t)u) << 16;
  return v.f;
}

__device__ __forceinline__ void async16(const void* g, void* l) {
  __builtin_amdgcn_global_load_lds(
      (const __attribute__((address_space(1))) void*)g,
      (__attribute__((address_space(3))) void*)l, 16, 0, 0);
}

// ---------------- setup / conversion kernels ----------------

__global__ void k_cast_f32_bf16(const float* __restrict__ src,
                                unsigned short* __restrict__ dst, int n4) {
  int i = blockIdx.x * 256 + threadIdx.x;
  if (i < n4) {
    float4 v = ((const float4*)src)[i];
    ushort4 o; o.x = f2b(v.x); o.y = f2b(v.y); o.z = f2b(v.z); o.w = f2b(v.w);
    ((ushort4*)dst)[i] = o;
  }
}

__global__ void k_build_wenc_t(const float* __restrict__ W,
                               unsigned short* __restrict__ WT) {
  // W: (512,256) row-major -> WT: (256,512) row-major (bf16)
  int i = blockIdx.x * 256 + threadIdx.x;
  if (i < ADIM * EDIM) {
    int a = i >> 9, k = i & 511;
    WT[i] = f2b(W[k * ADIM + a]);
  }
}

__global__ void k_build_wcat(const float* __restrict__ Wih,
                             const float* __restrict__ Whh,
                             unsigned short* __restrict__ Wcat) {
  int i = blockIdx.x * 256 + threadIdx.x;  // 2048*1536
  if (i < NGATE * KCAT) {
    int n = i / KCAT, k = i - n * KCAT;
    float v = (k < 1024) ? Wih[n * 1024 + k] : Whh[n * 512 + (k - 1024)];
    Wcat[i] = f2b(v);
  }
}

__global__ void k_build_wfc(const float* __restrict__ Wfc,
                            unsigned short* __restrict__ Wp) {
  int i = blockIdx.x * 256 + threadIdx.x;  // 30080*512
  if (i < VPAD * 512) {
    int n = i >> 9, k = i & 511;
    Wp[i] = (n < VDIM) ? f2b(Wfc[n * 512 + k]) : (unsigned short)0;
  }
}

__global__ void k_build_xemb(const int* __restrict__ cap,
                             const float* __restrict__ emb,
                             unsigned short* __restrict__ X) {
  int i = blockIdx.x * 256 + threadIdx.x;  // 20*128*512
  if (i < NSTEP * BSZ * EDIM) {
    int t = i / (BSZ * EDIM);
    int r = i - t * (BSZ * EDIM);
    int b = r >> 9, k = r & 511;
    int tok = cap[b * 21 + t];  // captions[:, :-1]
    X[((size_t)(t * BSZ + b)) * EDIM + k] = f2b(emb[(size_t)tok * EDIM + k]);
  }
}

__global__ void k_init_state(float* __restrict__ hc, float* __restrict__ cc,
                             unsigned short* __restrict__ XC) {
  int i = blockIdx.x * 256 + threadIdx.x;  // 65536
  if (i < BSZ * HDIM) {
    hc[i] = 0.f; cc[i] = 0.f;
    int b = i >> 9, k = i & 511;
    XC[(size_t)b * KSTEP + 512 + k] = 0;  // h-slice for t=0
  }
}

// ---------------- bf16 MFMA GEMM: C = A(MxK) * B(NxK)^T (+bias) ----------------
// 128x128 block tile, BK=32, 256 threads (4 waves, each 64x64 = 4x4 of 16x16x32).
// Optional split-K via blockIdx.z (kchunkB bytes per z, zstride floats per z-output).

template <bool OUT_BF16>
__global__ __launch_bounds__(256) void gemm_bt(
    const unsigned short* __restrict__ A, int ldaB,
    const unsigned short* __restrict__ Bm, int ldbB,
    void* __restrict__ C, int ldc, int Nreal,
    const float* __restrict__ bias, int kt, int kchunkB, size_t zstride) {
  __shared__ short As[128 * 32];
  __shared__ short Bs[128 * 32];
  const int tid = threadIdx.x;
  const int w = tid >> 6, lane = tid & 63;
  const int m0 = blockIdx.y * 128, n0 = blockIdx.x * 128;
  const int z = blockIdx.z;

  const char* Ab = (const char*)A + (size_t)z * kchunkB;
  const char* Bb = (const char*)Bm + (size_t)z * kchunkB;

  const int q0 = w, q1 = w + 4;
  const int rr = lane >> 2;        // row-within-16
  const int cbyte = (lane & 3) * 16;
  const char* gA0 = Ab + (size_t)(m0 + q0 * 16 + rr) * ldaB + cbyte;
  const char* gA1 = Ab + (size_t)(m0 + q1 * 16 + rr) * ldaB + cbyte;
  const char* gB0 = Bb + (size_t)(n0 + q0 * 16 + rr) * ldbB + cbyte;
  const char* gB1 = Bb + (size_t)(n0 + q1 * 16 + rr) * ldbB + cbyte;
  short* lA0 = &As[q0 * 512]; short* lA1 = &As[q1 * 512];
  short* lB0 = &Bs[q0 * 512]; short* lB1 = &Bs[q1 * 512];

  const int wm = w >> 1, wn = w & 1;
  const int fr = lane & 15, ko = (lane >> 4) * 8;

  f32x4 acc[4][4] = {};

  for (int kb = 0; kb < kt; ++kb) {
    const int kB = kb * 64;
    async16(gA0 + kB, lA0); async16(gA1 + kB, lA1);
    async16(gB0 + kB, lB0); async16(gB1 + kB, lB1);
    __syncthreads();  // compiler drains vmcnt before s_barrier
    short8 af[4], bfr[4];
#pragma unroll
    for (int i = 0; i < 4; ++i)
      af[i] = *(const short8*)&As[(wm * 64 + i * 16 + fr) * 32 + ko];
#pragma unroll
    for (int j = 0; j < 4; ++j)
      bfr[j] = *(const short8*)&Bs[(wn * 64 + j * 16 + fr) * 32 + ko];
#pragma unroll
    for (int i = 0; i < 4; ++i)
#pragma unroll
      for (int j = 0; j < 4; ++j)
        acc[i][j] = __builtin_amdgcn_mfma_f32_16x16x32_bf16(af[i], bfr[j], acc[i][j], 0, 0, 0);
    __syncthreads();
  }

  const int r4 = (lane >> 4) * 4;
  float* Cf = (float*)C + (size_t)z * zstride;
  unsigned short* Cb = (unsigned short*)C;
#pragma unroll
  for (int i = 0; i < 4; ++i) {
#pragma unroll
    for (int j = 0; j < 4; ++j) {
      int cc = n0 + wn * 64 + j * 16 + fr;
      if (cc < Nreal) {
        float bv = bias ? bias[cc] : 0.f;
        int r0 = m0 + wm * 64 + i * 16 + r4;
#pragma unroll
        for (int r = 0; r < 4; ++r) {
          float v = acc[i][j][r] + bv;
          if (OUT_BF16) Cb[(size_t)(r0 + r) * ldc + cc] = f2b(v);
          else          Cf[(size_t)(r0 + r) * ldc + cc] = v;
        }
      }
    }
  }
}

// ---------------- attention (standalone, t=0 only): 1 block per batch row ----
// hproj = h @ W_dec + b_dec ; e_p = relu(encproj+hproj)·w_full + b_full ;
// alpha = softmax_p(e) ; context = sum_p alpha_p * enc[b,p,:]  -> XC[t] bf16

__global__ __launch_bounds__(512) void k_attention(
    const float* __restrict__ h, const float* __restrict__ Wd,
    const float* __restrict__ bd, const float* __restrict__ wfull,
    const float* __restrict__ bfull,
    const unsigned short* __restrict__ EncP,  // 25088x256 bf16
    const unsigned short* __restrict__ EncB,  // 25088x512 bf16
    unsigned short* __restrict__ XCt)         // 128x1024 bf16 (slice t)
{
  __shared__ float hsh[512];
  __shared__ float hpp[512];
  __shared__ float hp[256];
  __shared__ float wsh[256];
  __shared__ float ebuf[200];
  __shared__ float sred[8];
  __shared__ float sM, sS;

  const int tid = threadIdx.x;
  const int b = blockIdx.x;
  const int w = tid >> 6, lane = tid & 63;

  hsh[tid] = h[b * 512 + tid];
  if (tid < 256) wsh[tid] = wfull[tid];
  __syncthreads();

  // phase 1: hproj (split k across two halves of the block)
  {
    const int a = tid & 255, half = tid >> 8;
    const float* wc = Wd + a;
    const int k0 = half * 256;
    float s0 = 0, s1 = 0, s2 = 0, s3 = 0;
    for (int k = k0; k < k0 + 256; k += 4) {
      s0 += hsh[k]     * wc[(k)     * 256];
      s1 += hsh[k + 1] * wc[(k + 1) * 256];
      s2 += hsh[k + 2] * wc[(k + 2) * 256];
      s3 += hsh[k + 3] * wc[(k + 3) * 256];
    }
    hpp[tid] = (s0 + s1) + (s2 + s3);
  }
  __syncthreads();
  if (tid < 256) hp[tid] = hpp[tid] + hpp[tid + 256] + bd[tid];
  __syncthreads();

  // phase 2: e_p, one wave per p (8 waves round-robin)
  const float bf0 = bfull[0];
  for (int p = w; p < PDIM; p += 8) {
    const unsigned short* row = EncP + ((size_t)(b * PDIM + p)) * 256;
    float s = 0.f;
#pragma unroll
    for (int jj = 0; jj < 4; ++jj) {
      int a = lane + jj * 64;
      float v = b2f(row[a]) + hp[a];
      s += fmaxf(v, 0.f) * wsh[a];
    }
#pragma unroll
    for (int off = 32; off; off >>= 1) s += __shfl_down(s, off, 64);
    if (lane == 0) ebuf[p] = s + bf0;
  }
  __syncthreads();

  // phase 3: softmax over p
  float m = -1e30f;
  for (int p = tid; p < PDIM; p += 512) m = fmaxf(m, ebuf[p]);
#pragma unroll
  for (int off = 32; off; off >>= 1) m = fmaxf(m, __shfl_down(m, off, 64));
  if (lane == 0) sred[w] = m;
  __syncthreads();
  if (tid == 0) {
    float mm = sred[0];
#pragma unroll
    for (int i = 1; i < 8; ++i) mm = fmaxf(mm, sred[i]);
    sM = mm;
  }
  __syncthreads();
  const float M = sM;
  float ps = 0.f;
  for (int p = tid; p < PDIM; p += 512) {
    float v = __expf(ebuf[p] - M); ebuf[p] = v; ps += v;
  }
#pragma unroll
  for (int off = 32; off; off >>= 1) ps += __shfl_down(ps, off, 64);
  if (lane == 0) sred[w] = ps;
  __syncthreads();
  if (tid == 0) {
    float ss = 0.f;
#pragma unroll
    for (int i = 0; i < 8; ++i) ss += sred[i];
    sS = 1.f / ss;
  }
  __syncthreads();
  const float inv = sS;

  // phase 4: context (each thread owns one e-column), 4-way ILP
  {
    const unsigned short* eb = EncB + (size_t)b * PDIM * 512 + tid;
    float c0 = 0.f, c1 = 0.f, c2 = 0.f, c3 = 0.f;
    for (int p = 0; p < PDIM; p += 4) {
      c0 += ebuf[p]     * b2f(eb[(p)     * 512]);
      c1 += ebuf[p + 1] * b2f(eb[(p + 1) * 512]);
      c2 += ebuf[p + 2] * b2f(eb[(p + 2) * 512]);
      c3 += ebuf[p + 3] * b2f(eb[(p + 3) * 512]);
    }
    XCt[(size_t)b * KSTEP + tid] = f2b(((c0 + c1) + (c2 + c3)) * inv);
  }
}

// ---------------- fused LSTM cell (t) + attention (t+1) ----------------
// 1 block per batch row, 512 threads. h never leaves LDS.

__global__ __launch_bounds__(512) void k_cell_attn(
    const float* __restrict__ Gpart,  // KSPLIT x 128 x 2048
    const float* __restrict__ XW,     // 2560 x 2048 (precomputed xt@Wih_x^T)
    const float* __restrict__ bih, const float* __restrict__ bhh,
    float* __restrict__ cc, unsigned short* __restrict__ Hall,
    const float* __restrict__ Wd, const float* __restrict__ bd,
    const float* __restrict__ wfull, const float* __restrict__ bfull,
    const unsigned short* __restrict__ EncP,
    const unsigned short* __restrict__ EncB,
    unsigned short* __restrict__ XCnext, int t) {
  __shared__ float hsh[512];
  __shared__ float hpp[512];
  __shared__ float hp[256];
  __shared__ float wsh[256];
  __shared__ float ebuf[200];
  __shared__ float sred[8];
  __shared__ float sM, sS;

  const int tid = threadIdx.x;
  const int b = blockIdx.x;
  const int w = tid >> 6, lane = tid & 63;

  if (tid < 256) wsh[tid] = wfull[tid];

  // ---- cell for (b, k=tid) ----
  {
    const int k = tid;
    const float* xw = XW + ((size_t)(t * BSZ + b)) * NGATE;
    float gI = bih[k]        + bhh[k]        + xw[k];
    float gF = bih[512 + k]  + bhh[512 + k]  + xw[512 + k];
    float gG = bih[1024 + k] + bhh[1024 + k] + xw[1024 + k];
    float gO = bih[1536 + k] + bhh[1536 + k] + xw[1536 + k];
    const float* P = Gpart + (size_t)b * NGATE + k;
#pragma unroll
    for (int z = 0; z < KSPLIT; ++z) {
      const float* Pz = P + (size_t)z * BSZ * NGATE;
      gI += Pz[0]; gF += Pz[512]; gG += Pz[1024]; gO += Pz[1536];
    }
    float cv = cc[b * 512 + k];
    float ig = 1.f / (1.f + __expf(-gI));
    float fg = 1.f / (1.f + __expf(-gF));
    float gg = tanhf(gG);
    float og = 1.f / (1.f + __expf(-gO));
    float cn = fg * cv + ig * gg;
    float hn = og * tanhf(cn);
    cc[b * 512 + k] = cn;
    Hall[((size_t)b * NSTEP + t) * 512 + k] = f2b(hn);
    hsh[k] = hn;
    if (t < NSTEP - 1) XCnext[(size_t)b * KSTEP + 512 + k] = f2b(hn);
  }
  __syncthreads();
  if (t >= NSTEP - 1) return;

  // ---- attention for step t+1 (h from LDS) ----

  // phase 1: hproj
  {
    const int a = tid & 255, half = tid >> 8;
    const float* wc = Wd + a;
    const int k0 = half * 256;
    float s0 = 0, s1 = 0, s2 = 0, s3 = 0;
    for (int k = k0; k < k0 + 256; k += 4) {
      s0 += hsh[k]     * wc[(k)     * 256];
      s1 += hsh[k + 1] * wc[(k + 1) * 256];
      s2 += hsh[k + 2] * wc[(k + 2) * 256];
      s3 += hsh[k + 3] * wc[(k + 3) * 256];
    }
    hpp[tid] = (s0 + s1) + (s2 + s3);
  }
  __syncthreads();
  if (tid < 256) hp[tid] = hpp[tid] + hpp[tid + 256] + bd[tid];
  __syncthreads();

  // phase 2: e_p
  const float bf0 = bfull[0];
  for (int p = w; p < PDIM; p += 8) {
    const unsigned short* row = EncP + ((size_t)(b * PDIM + p)) * 256;
    float s = 0.f;
#pragma unroll
    for (int jj = 0; jj < 4; ++jj) {
      int a = lane + jj * 64;
      float v = b2f(row[a]) + hp[a];
      s += fmaxf(v, 0.f) * wsh[a];
    }
#pragma unroll
    for (int off = 32; off; off >>= 1) s += __shfl_down(s, off, 64);
    if (lane == 0) ebuf[p] = s + bf0;
  }
  __syncthreads();

  // phase 3: softmax over p
  float m = -1e30f;
  for (int p = tid; p < PDIM; p += 512) m = fmaxf(m, ebuf[p]);
#pragma unroll
  for (int off = 32; off; off >>= 1) m = fmaxf(m, __shfl_down(m, off, 64));
  if (lane == 0) sred[w] = m;
  __syncthreads();
  if (tid == 0) {
    float mm = sred[0];
#pragma unroll
    for (int i = 1; i < 8; ++i) mm = fmaxf(mm, sred[i]);
    sM = mm;
  }
  __syncthreads();
  const float M = sM;
  float ps = 0.f;
  for (int p = tid; p < PDIM; p += 512) {
    float v = __expf(ebuf[p] - M); ebuf[p] = v; ps += v;
  }
#pragma unroll
  for (int off = 32; off; off >>= 1) ps += __shfl_down(ps, off, 64);
  if (lane == 0) sred[w] = ps;
  __syncthreads();
  if (tid == 0) {
    float ss = 0.f;
#pragma unroll
    for (int i = 0; i < 8; ++i) ss += sred[i];
    sS = 1.f / ss;
  }
  __syncthreads();
  const float inv = sS;

  // phase 4: context, 4-way ILP
  {
    const unsigned short* eb = EncB + (size_t)b * PDIM * 512 + tid;
    float c0 = 0.f, c1 = 0.f, c2 = 0.f, c3 = 0.f;
    for (int p = 0; p < PDIM; p += 4) {
      c0 += ebuf[p]     * b2f(eb[(p)     * 512]);
      c1 += ebuf[p + 1] * b2f(eb[(p + 1) * 512]);
      c2 += ebuf[p + 2] * b2f(eb[(p + 2) * 512]);
      c3 += ebuf[p + 3] * b2f(eb[(p + 3) * 512]);
    }
    XCnext[(size_t)b * KSTEP + tid] = f2b(((c0 + c1) + (c2 + c3)) * inv);
  }
}

// ---------------- launch ----------------

extern "C" void kernel_launch(void* const* d_in, const int* in_sizes, int n_in,
                              void* d_out, int out_size, void* d_ws, size_t ws_size,
                              hipStream_t stream) {
  const float* enc   = (const float*)d_in[0];
  const int*   cap   = (const int*)d_in[1];
  const float* emb   = (const float*)d_in[2];
  const float* Wenc  = (const float*)d_in[3];
  const float* benc  = (const float*)d_in[4];
  const float* Wdec  = (const float*)d_in[5];
  const float* bdec  = (const float*)d_in[6];
  const float* wfull = (const float*)d_in[7];
  const float* bfull = (const float*)d_in[8];
  const float* Wih   = (const float*)d_in[9];
  const float* bih   = (const float*)d_in[10];
  const float* Whh   = (const float*)d_in[11];
  const float* bhh   = (const float*)d_in[12];
  const float* Wfc   = (const float*)d_in[13];
  const float* bfc   = (const float*)d_in[14];
  float* out = (float*)d_out;

  char* ws = (char*)d_ws;
  size_t off = 0;
  auto alloc = [&](size_t bytes) {
    char* p = ws + off;
    off += (bytes + 255) & ~(size_t)255;
    return p;
  };
  unsigned short* Wcat  = (unsigned short*)alloc((size_t)NGATE * KCAT * 2);
  unsigned short* Wfcb  = (unsigned short*)alloc((size_t)VPAD * 512 * 2);
  unsigned short* WencT = (unsigned short*)alloc((size_t)ADIM * EDIM * 2);
  unsigned short* EncB  = (unsigned short*)alloc((size_t)BSZ * PDIM * EDIM * 2);
  unsigned short* EncP  = (unsigned short*)alloc((size_t)BSZ * PDIM * ADIM * 2);
  unsigned short* XC    = (unsigned short*)alloc((size_t)NSTEP * BSZ * KSTEP * 2);
  unsigned short* Xemb  = (unsigned short*)alloc((size_t)NSTEP * BSZ * EDIM * 2);
  float* XW             = (float*)alloc((size_t)NSTEP * BSZ * NGATE * 4);
  float* Gpart          = (float*)alloc((size_t)KSPLIT * BSZ * NGATE * 4);
  float* hc             = (float*)alloc((size_t)BSZ * HDIM * 4);
  float* ccst           = (float*)alloc((size_t)BSZ * HDIM * 4);
  unsigned short* Hall  = (unsigned short*)alloc((size_t)NSTEP * BSZ * HDIM * 2);
  (void)ws_size; (void)in_sizes; (void)n_in; (void)out_size;

  // setup
  {
    int n4 = BSZ * PDIM * EDIM / 4;
    k_cast_f32_bf16<<<(n4 + 255) / 256, 256, 0, stream>>>(enc, EncB, n4);
  }
  k_build_wenc_t<<<(ADIM * EDIM + 255) / 256, 256, 0, stream>>>(Wenc, WencT);
  k_build_wcat<<<(NGATE * KCAT + 255) / 256, 256, 0, stream>>>(Wih, Whh, Wcat);
  k_build_wfc<<<(VPAD * 512 + 255) / 256, 256, 0, stream>>>(Wfc, Wfcb);
  k_build_xemb<<<(NSTEP * BSZ * EDIM + 255) / 256, 256, 0, stream>>>(cap, emb, Xemb);
  k_init_state<<<(BSZ * HDIM + 255) / 256, 256, 0, stream>>>(hc, ccst, XC);

  // enc_proj: (25088x256 bf16) = EncB(25088x512) @ WencT(256x512)^T + benc
  gemm_bt<true><<<dim3(2, 196, 1), 256, 0, stream>>>(
      EncB, EDIM * 2, WencT, EDIM * 2, EncP, ADIM, ADIM, benc, 16, 0, 0);

  // XW: (2560x2048) = Xemb(2560x512) @ Wcat[:, :512]^T  (xt contribution, all steps)
  gemm_bt<false><<<dim3(NGATE / 128, NSTEP * BSZ / 128, 1), 256, 0, stream>>>(
      Xemb, EDIM * 2, Wcat, KCAT * 2, XW, NGATE, NGATE, nullptr, 16, 0, 0);

  // t=0 attention (h = 0)
  k_attention<<<128, 512, 0, stream>>>(hc, Wdec, bdec, wfull, bfull, EncP, EncB, XC);

  for (int t = 0; t < NSTEP; ++t) {
    unsigned short* XCt = XC + (size_t)t * BSZ * KSTEP;
    // gates partials over K=1024 ([context|h] vs Wcat[:, 512:1536]): split-K=8
    gemm_bt<false><<<dim3(NGATE / 128, 1, KSPLIT), 256, 0, stream>>>(
        XCt, KSTEP * 2, Wcat + 512, KCAT * 2, Gpart, NGATE, NGATE, nullptr,
        (KSTEP / KSPLIT) / 32, (KSTEP / KSPLIT) * 2, (size_t)BSZ * NGATE);
    unsigned short* XCn = XC + (size_t)((t + 1 < NSTEP) ? (t + 1) : 0) * BSZ * KSTEP;
    k_cell_attn<<<128, 512, 0, stream>>>(Gpart, XW, bih, bhh, ccst, Hall,
                                         Wdec, bdec, wfull, bfull, EncP, EncB, XCn, t);
  }

  // FC head: out(2560x30000) = Hall(2560x512) @ Wfcb(30080x512)^T + bfc
  gemm_bt<false><<<dim3(VPAD / 128, NSTEP * BSZ / 128, 1), 256, 0, stream>>>(
      Hall, HDIM * 2, Wfcb, HDIM * 2, out, VDIM, VDIM, bfc, 16, 0, 0);
}